// Round 3
// baseline (1503.185 us; speedup 1.0000x reference)
//
#include <hip/hip_runtime.h>
#include <hip/hip_bf16.h>
#include <stdint.h>

// 2-layer GCN + global mean pool + MLP head. N=100000, E=1600000, G=512. fp32.
//
// Layer 1 input is [N,1] => layer-1 aggregation collapses to scalar t[i]:
//   t[i] = sum_{e: dst=i} x[src]*dinv[src]*dinv[i]  (self-loop added in k_xw2)
// Layer 2: xw2 = relu(t*W1+b1) @ W2 [N,128]; aggregation via bucket-grouped edges
// with LDS accumulators (no CSR, no global atomics).
//
// Edge grouping (bucket = dst>>6, 64 nodes/bucket) is a contention-free counting
// sort: per-chunk LDS histogram -> cross-chunk scan -> ordered scatter with
// block-private LDS cursors. Round-2 lesson: global atomic cursors over few
// lines serialize (~16K RMW/line) and adjacent-8B-slot writes from different
// XCDs amplify writebacks 6.5x; this design has zero global atomics.

#define CHUNK   8192
#define MAXBUCK 1600

static inline size_t align_up(size_t x, size_t a){ return (x + a - 1) & ~(a - 1); }

// --- Pass A: per-chunk bucket histogram (LDS) ---
__global__ void __launch_bounds__(256) k_hist(const int* __restrict__ dst,
                                              int* __restrict__ hist, int E, int nbuck){
    __shared__ int h[MAXBUCK];
    for (int i = threadIdx.x; i < nbuck; i += 256) h[i] = 0;
    __syncthreads();
    int base = blockIdx.x * CHUNK;
    int end = min(base + CHUNK, E);
    for (int i = base + threadIdx.x; i < end; i += 256)
        atomicAdd(&h[dst[i] >> 6], 1);
    __syncthreads();
    int* row = hist + (size_t)blockIdx.x * nbuck;
    for (int i = threadIdx.x; i < nbuck; i += 256) row[i] = h[i];
}

// --- Pass B1: per-bucket running offset across chunks; bucket totals ---
__global__ void k_cscanA(int* __restrict__ hist, int* __restrict__ btot,
                         int nch, int nbuck){
    int b = blockIdx.x * 256 + threadIdx.x;
    if (b >= nbuck) return;
    int run = 0;
    #pragma unroll 4
    for (int c = 0; c < nch; ++c){
        int* p = hist + (size_t)c * nbuck + b;
        int t = *p;
        *p = run;
        run += t;
    }
    btot[b] = run;
}

// --- Pass B2: exclusive scan of bucket totals -> bucket base offsets ---
__global__ void k_cscanB(const int* __restrict__ btot, int* __restrict__ babs,
                         int nbuck, int E){
    __shared__ int sh[256];
    int t = threadIdx.x;
    int it = (nbuck + 255) / 256;  // <= 16
    int v[16];
    int sum = 0;
    int base = t * it;
    for (int u = 0; u < it; ++u){
        int idx = base + u;
        v[u] = (idx < nbuck) ? btot[idx] : 0;
        sum += v[u];
    }
    sh[t] = sum; __syncthreads();
    for (int off = 1; off < 256; off <<= 1){
        int xv = (t >= off) ? sh[t - off] : 0;
        __syncthreads();
        if (t >= off) sh[t] += xv;
        __syncthreads();
    }
    int run = (t == 0) ? 0 : sh[t - 1];
    for (int u = 0; u < it; ++u){
        int idx = base + u;
        if (idx < nbuck) babs[idx] = run;
        run += v[u];
    }
    if (t == 0) babs[nbuck] = E;
}

// --- Pass C: ordered scatter into bucket-grouped ebuf (LDS cursors) ---
__global__ void __launch_bounds__(256) k_scatter(
        const int* __restrict__ src, const int* __restrict__ dst,
        const int* __restrict__ hist, const int* __restrict__ babs,
        int2* __restrict__ ebuf, int E, int nbuck){
    __shared__ int lcur[MAXBUCK];
    const int* rel = hist + (size_t)blockIdx.x * nbuck;
    for (int i = threadIdx.x; i < nbuck; i += 256) lcur[i] = babs[i] + rel[i];
    __syncthreads();
    int base = blockIdx.x * CHUNK;
    int end = min(base + CHUNK, E);
    for (int i = base + threadIdx.x; i < end; i += 256){
        int s = src[i], d = dst[i];
        int slot = atomicAdd(&lcur[d >> 6], 1);
        ebuf[slot] = make_int2(s, d);
    }
}

// --- degree + dinv from sorted ebuf (replaces global-atomic k_count) ---
__global__ void __launch_bounds__(256) k_deg_dinv(
        const int2* __restrict__ ebuf, const int* __restrict__ babs,
        float* __restrict__ dinv, int N){
    __shared__ int cnt[64];
    int b = blockIdx.x, node0 = b << 6, t = threadIdx.x;
    if (t < 64) cnt[t] = 0;
    __syncthreads();
    int beg = babs[b], end = babs[b + 1];
    for (int i = beg + t; i < end; i += 256)
        atomicAdd(&cnt[ebuf[i].y & 63], 1);
    __syncthreads();
    if (t < 64 && node0 + t < N)
        dinv[node0 + t] = rsqrtf((float)cnt[t] + 1.0f);
}

// --- layer-1 scalar aggregation t[i] (LDS accumulation per bucket) ---
__global__ void __launch_bounds__(256) k_tacc(
        const int2* __restrict__ ebuf, const int* __restrict__ babs,
        const float* __restrict__ x, const float* __restrict__ dinv,
        float* __restrict__ tacc, int N){
    __shared__ float tl[64];
    __shared__ float dl[64];
    int b = blockIdx.x, node0 = b << 6, t = threadIdx.x;
    if (t < 64){
        tl[t] = 0.f;
        int n = node0 + t;
        dl[t] = (n < N) ? dinv[n] : 0.f;
    }
    __syncthreads();
    int beg = babs[b], end = babs[b + 1];
    for (int i = beg + t; i < end; i += 256){
        int2 e = ebuf[i];
        int j = e.y & 63;
        atomicAdd(&tl[j], x[e.x] * dinv[e.x] * dl[j]);
    }
    __syncthreads();
    if (t < 64 && node0 + t < N) tacc[node0 + t] = tl[t];
}

// xw2[i,:] = relu(t[i]*W1 + b1) @ W2, 128 cols. 256 threads = 2 nodes.
__global__ void __launch_bounds__(256) k_xw2(
        const float* __restrict__ x, const float* __restrict__ dinv,
        const float* __restrict__ tacc,
        const float* __restrict__ W1, const float* __restrict__ b1,
        const float* __restrict__ W2, float* __restrict__ xw2, int N){
    int col = threadIdx.x & 127;
    int sub = threadIdx.x >> 7;
    float w2c[64];
    #pragma unroll
    for (int j = 0; j < 64; ++j) w2c[j] = W2[j * 128 + col];
    int npairs = (N + 1) >> 1;
    for (int p = blockIdx.x; p < npairs; p += gridDim.x){
        int i = p * 2 + sub;
        if (i < N){
            float di = dinv[i];
            float tv = fmaf(x[i] * di, di, tacc[i]);
            float acc = 0.f;
            #pragma unroll
            for (int j = 0; j < 64; ++j){
                float h = fmaxf(fmaf(tv, W1[j], b1[j]), 0.f);
                acc = fmaf(h, w2c[j], acc);
            }
            xw2[(size_t)i * 128 + col] = acc;
        }
    }
}

// --- layer-2 aggregation: block per bucket, 64x128 fp32 LDS accumulator ---
// wave per edge: lane handles cols (lane, lane+64) -> bank-conflict-free ds_add.
__global__ void __launch_bounds__(256) k_agg2b(
        const int2* __restrict__ ebuf, const int* __restrict__ babs,
        const float* __restrict__ dinv, const float* __restrict__ xw2,
        const float* __restrict__ b2, float* __restrict__ h2, int N){
    __shared__ float acc[64 * 128];
    __shared__ float dl[64];
    int b = blockIdx.x, node0 = b << 6, t = threadIdx.x;
    for (int i = t; i < 64 * 128; i += 256) acc[i] = 0.f;
    if (t < 64){
        int n = node0 + t;
        dl[t] = (n < N) ? dinv[n] : 0.f;
    }
    __syncthreads();
    int beg = babs[b], end = babs[b + 1];
    int lane = t & 63, wid = t >> 6;
    int k = beg + wid;
    for (; k + 4 < end; k += 8){
        int2 e0 = ebuf[k];
        int2 e1 = ebuf[k + 4];
        float n0 = dinv[e0.x] * dl[e0.y & 63];
        float n1 = dinv[e1.x] * dl[e1.y & 63];
        float va0 = xw2[(size_t)e0.x * 128 + lane];
        float vb0 = xw2[(size_t)e0.x * 128 + 64 + lane];
        float va1 = xw2[(size_t)e1.x * 128 + lane];
        float vb1 = xw2[(size_t)e1.x * 128 + 64 + lane];
        int j0 = (e0.y & 63) << 7, j1 = (e1.y & 63) << 7;
        atomicAdd(&acc[j0 + lane],      va0 * n0);
        atomicAdd(&acc[j0 + 64 + lane], vb0 * n0);
        atomicAdd(&acc[j1 + lane],      va1 * n1);
        atomicAdd(&acc[j1 + 64 + lane], vb1 * n1);
    }
    for (; k < end; k += 4){
        int2 e0 = ebuf[k];
        float n0 = dinv[e0.x] * dl[e0.y & 63];
        float va0 = xw2[(size_t)e0.x * 128 + lane];
        float vb0 = xw2[(size_t)e0.x * 128 + 64 + lane];
        int j0 = (e0.y & 63) << 7;
        atomicAdd(&acc[j0 + lane],      va0 * n0);
        atomicAdd(&acc[j0 + 64 + lane], vb0 * n0);
    }
    __syncthreads();
    int nn = min(64, N - node0);
    int tot = nn << 7;
    for (int idx = t; idx < tot; idx += 256){
        int j = idx >> 7, c = idx & 127;
        float self = xw2[(size_t)(node0 + j) * 128 + c] * dl[j] * dl[j];
        float v = acc[idx] + self + b2[c];
        h2[(size_t)node0 * 128 + idx] = fmaxf(v, 0.f);
    }
}

// One block per graph: mean pool (binary search on sorted batch) + 2-layer head.
__global__ void __launch_bounds__(128) k_poolhead(
        const float* __restrict__ h2, const int* __restrict__ batch,
        const float* __restrict__ Wl1, const float* __restrict__ bl1,
        const float* __restrict__ Wl2, const float* __restrict__ bl2,
        float* __restrict__ out, int N){
    __shared__ float pooled[128];
    __shared__ float h3s[64];
    int g = blockIdx.x;
    int c = threadIdx.x;  // 128 threads
    int lo = 0, hi = N;
    while (lo < hi){ int m = (lo + hi) >> 1; if (batch[m] < g) lo = m + 1; else hi = m; }
    int lo2 = lo, hi2 = N;
    while (lo2 < hi2){ int m = (lo2 + hi2) >> 1; if (batch[m] < g + 1) lo2 = m + 1; else hi2 = m; }
    float acc = 0.f;
    for (int i = lo; i < lo2; ++i) acc += h2[(size_t)i * 128 + c];
    int cnt = lo2 - lo;
    pooled[c] = acc / (float)(cnt > 0 ? cnt : 1);
    __syncthreads();
    if (c < 64){
        float a = bl1[c];
        #pragma unroll
        for (int k = 0; k < 128; ++k) a = fmaf(pooled[k], Wl1[k * 64 + c], a);
        h3s[c] = fmaxf(a, 0.f);
    }
    __syncthreads();
    if (c < 4){
        float o = bl2[c];
        #pragma unroll
        for (int j = 0; j < 64; ++j) o = fmaf(h3s[j], Wl2[j * 4 + c], o);
        out[g * 4 + c] = o;
    }
}

extern "C" void kernel_launch(void* const* d_in, const int* in_sizes, int n_in,
                              void* d_out, int out_size, void* d_ws, size_t ws_size,
                              hipStream_t stream) {
    const float* x    = (const float*)d_in[0];
    const int*   ei   = (const int*)d_in[1];
    const int*   batch= (const int*)d_in[2];
    const float* W1   = (const float*)d_in[3];
    const float* b1   = (const float*)d_in[4];
    const float* W2   = (const float*)d_in[5];
    const float* b2   = (const float*)d_in[6];
    const float* Wl1  = (const float*)d_in[7];
    const float* bl1  = (const float*)d_in[8];
    const float* Wl2  = (const float*)d_in[9];
    const float* bl2  = (const float*)d_in[10];

    const int N = in_sizes[0];
    const int E = in_sizes[1] / 2;
    const int G = out_size / 4;
    const int* src = ei;
    const int* dst = ei + E;
    const int NBUCK = (N + 63) >> 6;            // 1563
    const int NCH   = (E + CHUNK - 1) / CHUNK;  // 196

    // Workspace layout (re-poisoned each call; every buffer fully written by kernels)
    char* p = (char*)d_ws;
    size_t off = 0;
    int*   hist = (int*)(p + off);   off += align_up((size_t)NCH * NBUCK * 4, 16);
    int*   btot = (int*)(p + off);   off += align_up((size_t)NBUCK * 4, 16);
    int*   babs = (int*)(p + off);   off += align_up((size_t)(NBUCK + 1) * 4, 16);
    float* dinv = (float*)(p + off); off += align_up((size_t)N * 4, 16);
    float* tacc = (float*)(p + off); off += align_up((size_t)N * 4, 16);
    int2*  ebuf = (int2*)(p + off);  off += align_up((size_t)E * 8, 16);
    float* xw2  = (float*)(p + off); off += align_up((size_t)N * 128 * 4, 16);
    float* h2   = (float*)(p + off); off += align_up((size_t)N * 128 * 4, 16);
    (void)ws_size; (void)n_in;

    k_hist    <<<NCH, 256, 0, stream>>>(dst, hist, E, NBUCK);
    k_cscanA  <<<(NBUCK + 255) / 256, 256, 0, stream>>>(hist, btot, NCH, NBUCK);
    k_cscanB  <<<1, 256, 0, stream>>>(btot, babs, NBUCK, E);
    k_scatter <<<NCH, 256, 0, stream>>>(src, dst, hist, babs, ebuf, E, NBUCK);
    k_deg_dinv<<<NBUCK, 256, 0, stream>>>(ebuf, babs, dinv, N);
    k_tacc    <<<NBUCK, 256, 0, stream>>>(ebuf, babs, x, dinv, tacc, N);
    k_xw2     <<<4096, 256, 0, stream>>>(x, dinv, tacc, W1, b1, W2, xw2, N);
    k_agg2b   <<<NBUCK, 256, 0, stream>>>(ebuf, babs, dinv, xw2, b2, h2, N);
    k_poolhead<<<G, 128, 0, stream>>>(h2, batch, Wl1, bl1, Wl2, bl2, (float*)d_out, N);
}

// Round 4
// 852.996 us; speedup vs baseline: 1.7622x; 1.7622x over previous
//
#include <hip/hip_runtime.h>
#include <hip/hip_bf16.h>
#include <stdint.h>

// 2-layer GCN + global mean pool + MLP head. N=100000, E=1600000, G=512. fp32.
//
// Key algebra:
//  - Layer 1 input is [N,1] -> layer-1 aggregation is a scalar t[i];
//    with xd[i]=x[i]*dinv[i]:  t[d] = dinv[d]*(sum_{e:dst=d} xd[src] + xd[d])
//  - h1s[i,:] = dinv[i]*relu(t[i]*W1+b1)  (pre-scaled by src dinv)
//  - Layer 2 uses associativity: A*(h1@W2) = (A*h1)@W2, so we aggregate the
//    64-col h1s (half the gather bytes of xw2) and apply W2 AFTER aggregation:
//    agg1[d,:] = dinv[d]*(sum_e h1s[src] + h1s[d]);  h2 = relu(agg1@W2 + b2)
//  - h2 never materialized: GEMM+mean-pool+MLP head fused, one block per graph.
//
// Round-3 lesson: gather kernel was latency-bound (33% occ, ~2 edges in flight).
// Fix: 16 KB LDS accumulator + 8-deep explicit load pipeline + 1-load-1-dsadd
// per edge (scale folding).  Edge grouping by dst-bucket (64 nodes) via
// contention-free counting sort (zero global atomics).

#define CHUNK   8192
#define MAXBUCK 1600

static inline size_t align_up(size_t x, size_t a){ return (x + a - 1) & ~(a - 1); }

// --- Pass A: per-chunk bucket histogram (LDS) ---
__global__ void __launch_bounds__(256) k_hist(const int* __restrict__ dst,
                                              int* __restrict__ hist, int E, int nbuck){
    __shared__ int h[MAXBUCK];
    for (int i = threadIdx.x; i < nbuck; i += 256) h[i] = 0;
    __syncthreads();
    int base = blockIdx.x * CHUNK;
    int end = min(base + CHUNK, E);
    for (int i = base + threadIdx.x; i < end; i += 256)
        atomicAdd(&h[dst[i] >> 6], 1);
    __syncthreads();
    int* row = hist + (size_t)blockIdx.x * nbuck;
    for (int i = threadIdx.x; i < nbuck; i += 256) row[i] = h[i];
}

// --- Pass B1: per-bucket running offset across chunks; bucket totals ---
__global__ void k_cscanA(int* __restrict__ hist, int* __restrict__ btot,
                         int nch, int nbuck){
    int b = blockIdx.x * 256 + threadIdx.x;
    if (b >= nbuck) return;
    int run = 0;
    #pragma unroll 4
    for (int c = 0; c < nch; ++c){
        int* p = hist + (size_t)c * nbuck + b;
        int t = *p;
        *p = run;
        run += t;
    }
    btot[b] = run;
}

// --- Pass B2: exclusive scan of bucket totals -> bucket base offsets ---
__global__ void k_cscanB(const int* __restrict__ btot, int* __restrict__ babs,
                         int nbuck, int E){
    __shared__ int sh[256];
    int t = threadIdx.x;
    int it = (nbuck + 255) / 256;  // <= 16
    int v[16];
    int sum = 0;
    int base = t * it;
    for (int u = 0; u < it; ++u){
        int idx = base + u;
        v[u] = (idx < nbuck) ? btot[idx] : 0;
        sum += v[u];
    }
    sh[t] = sum; __syncthreads();
    for (int off = 1; off < 256; off <<= 1){
        int xv = (t >= off) ? sh[t - off] : 0;
        __syncthreads();
        if (t >= off) sh[t] += xv;
        __syncthreads();
    }
    int run = (t == 0) ? 0 : sh[t - 1];
    for (int u = 0; u < it; ++u){
        int idx = base + u;
        if (idx < nbuck) babs[idx] = run;
        run += v[u];
    }
    if (t == 0) babs[nbuck] = E;
}

// --- Pass C: ordered scatter into bucket-grouped ebuf (block-private LDS cursors) ---
__global__ void __launch_bounds__(256) k_scatter(
        const int* __restrict__ src, const int* __restrict__ dst,
        const int* __restrict__ hist, const int* __restrict__ babs,
        int2* __restrict__ ebuf, int E, int nbuck){
    __shared__ int lcur[MAXBUCK];
    const int* rel = hist + (size_t)blockIdx.x * nbuck;
    for (int i = threadIdx.x; i < nbuck; i += 256) lcur[i] = babs[i] + rel[i];
    __syncthreads();
    int base = blockIdx.x * CHUNK;
    int end = min(base + CHUNK, E);
    for (int i = base + threadIdx.x; i < end; i += 256){
        int s = src[i], d = dst[i];
        int slot = atomicAdd(&lcur[d >> 6], 1);
        ebuf[slot] = make_int2(s, d);
    }
}

// --- degree -> dinv, xd = x*dinv (per bucket, LDS counters) ---
__global__ void __launch_bounds__(256) k_deg_dinv(
        const int2* __restrict__ ebuf, const int* __restrict__ babs,
        const float* __restrict__ x, float* __restrict__ dinv,
        float* __restrict__ xd, int N){
    __shared__ int cnt[64];
    int b = blockIdx.x, node0 = b << 6, t = threadIdx.x;
    if (t < 64) cnt[t] = 0;
    __syncthreads();
    int beg = babs[b], end = babs[b + 1];
    for (int i = beg + t; i < end; i += 256)
        atomicAdd(&cnt[ebuf[i].y & 63], 1);
    __syncthreads();
    if (t < 64 && node0 + t < N){
        float di = rsqrtf((float)cnt[t] + 1.0f);
        dinv[node0 + t] = di;
        xd[node0 + t] = x[node0 + t] * di;
    }
}

// --- layer-1 scalar + h1s rows: h1s[n,c] = dinv[n]*relu(t[n]*W1[c]+b1[c]) ---
__global__ void __launch_bounds__(256) k_tacc_h1(
        const int2* __restrict__ ebuf, const int* __restrict__ babs,
        const float* __restrict__ xd, const float* __restrict__ dinv,
        const float* __restrict__ W1, const float* __restrict__ b1,
        float* __restrict__ h1s, int N){
    __shared__ float tl[64], dl[64], tf[64], w1s[64], b1s[64];
    int b = blockIdx.x, node0 = b << 6, t = threadIdx.x;
    if (t < 64){
        tl[t] = 0.f;
        int n = node0 + t;
        dl[t] = (n < N) ? dinv[n] : 0.f;
        w1s[t] = W1[t];
        b1s[t] = b1[t];
    }
    __syncthreads();
    int beg = babs[b], end = babs[b + 1];
    for (int i = beg + t; i < end; i += 256){
        int2 e = ebuf[i];
        atomicAdd(&tl[e.y & 63], xd[e.x]);
    }
    __syncthreads();
    if (t < 64){
        int n = node0 + t;
        tf[t] = (n < N) ? dl[t] * (tl[t] + xd[n]) : 0.f;
    }
    __syncthreads();
    int nn = min(64, N - node0);
    int tot = nn << 6;
    for (int idx = t; idx < tot; idx += 256){
        int j = idx >> 6, c = idx & 63;
        float h = fmaxf(fmaf(tf[j], w1s[c], b1s[c]), 0.f);
        h1s[((size_t)node0 << 6) + idx] = dl[j] * h;
    }
}

// --- layer-2 aggregation over h1s: block per bucket, 64x64 LDS acc (16 KB),
//     8-deep pipelined gather, 1 load + 1 ds_add per edge ---
__global__ void __launch_bounds__(256) k_agg1(
        const int2* __restrict__ ebuf, const int* __restrict__ babs,
        const float* __restrict__ dinv, const float* __restrict__ h1s,
        float* __restrict__ agg1, int N){
    __shared__ float acc[64 * 64];
    __shared__ float dl[64];
    int b = blockIdx.x, node0 = b << 6, t = threadIdx.x;
    for (int i = t; i < 64 * 64; i += 256) acc[i] = 0.f;
    if (t < 64){
        int n = node0 + t;
        dl[t] = (n < N) ? dinv[n] : 0.f;
    }
    __syncthreads();
    int beg = babs[b], end = babs[b + 1];
    int lane = t & 63, wid = t >> 6;
    int k = beg + wid;
    for (; k + 28 < end; k += 32){
        int2 e[8];
        float hv[8];
        #pragma unroll
        for (int u = 0; u < 8; ++u) e[u] = ebuf[k + 4 * u];
        #pragma unroll
        for (int u = 0; u < 8; ++u) hv[u] = h1s[((size_t)e[u].x << 6) + lane];
        #pragma unroll
        for (int u = 0; u < 8; ++u)
            atomicAdd(&acc[((e[u].y & 63) << 6) + lane], hv[u]);
    }
    for (; k < end; k += 4){
        int2 e = ebuf[k];
        atomicAdd(&acc[((e.y & 63) << 6) + lane], h1s[((size_t)e.x << 6) + lane]);
    }
    __syncthreads();
    int nn = min(64, N - node0);
    int tot = nn << 6;
    for (int idx = t; idx < tot; idx += 256){
        int j = idx >> 6;
        float v = acc[idx] + h1s[((size_t)node0 << 6) + idx];  // self term (h1s already dinv[src]-scaled)
        agg1[((size_t)node0 << 6) + idx] = dl[j] * v;
    }
}

// --- fused: h2 = relu(agg1@W2+b2) -> mean pool -> MLP head. Block per graph. ---
__global__ void __launch_bounds__(256) k_gemm_pool(
        const float* __restrict__ agg1, const int* __restrict__ batch,
        const float* __restrict__ W2, const float* __restrict__ b2,
        const float* __restrict__ Wl1, const float* __restrict__ bl1,
        const float* __restrict__ Wl2, const float* __restrict__ bl2,
        float* __restrict__ out, int N){
    __shared__ float rows[2][64];
    __shared__ float poolsh[256];
    __shared__ float pooled[128];
    __shared__ float h3s[64];
    int g = blockIdx.x;
    int t = threadIdx.x;
    int c = t & 127, sub = t >> 7;
    int lo = 0, hi = N;
    while (lo < hi){ int m = (lo + hi) >> 1; if (batch[m] < g) lo = m + 1; else hi = m; }
    int lo2 = lo, hi2 = N;
    while (lo2 < hi2){ int m = (lo2 + hi2) >> 1; if (batch[m] < g + 1) lo2 = m + 1; else hi2 = m; }
    int cnt = lo2 - lo;
    float w2c[64];
    #pragma unroll
    for (int j = 0; j < 64; ++j) w2c[j] = W2[j * 128 + c];
    float b2c = b2[c];
    float pool = 0.f;
    int npairs = (cnt + 1) >> 1;
    for (int p = 0; p < npairs; ++p){
        int i0 = lo + 2 * p;
        // stage rows i0 (threads 0..63) and i0+1 (threads 128..191)
        if (t < 64) rows[0][t] = agg1[((size_t)i0 << 6) + t];
        else if (t >= 128 && t < 192)
            rows[1][t - 128] = (i0 + 1 < lo2) ? agg1[((size_t)(i0 + 1) << 6) + (t - 128)] : 0.f;
        __syncthreads();
        int i = i0 + sub;
        if (i < lo2){
            float a = b2c;
            #pragma unroll
            for (int j = 0; j < 64; ++j) a = fmaf(rows[sub][j], w2c[j], a);
            pool += fmaxf(a, 0.f);
        }
        __syncthreads();
    }
    poolsh[t] = pool;
    __syncthreads();
    if (t < 128){
        float s = poolsh[t] + poolsh[t + 128];
        pooled[t] = s / (float)(cnt > 0 ? cnt : 1);
    }
    __syncthreads();
    if (t < 64){
        float a = bl1[t];
        #pragma unroll
        for (int k = 0; k < 128; ++k) a = fmaf(pooled[k], Wl1[k * 64 + t], a);
        h3s[t] = fmaxf(a, 0.f);
    }
    __syncthreads();
    if (t < 4){
        float o = bl2[t];
        #pragma unroll
        for (int j = 0; j < 64; ++j) o = fmaf(h3s[j], Wl2[j * 4 + t], o);
        out[g * 4 + t] = o;
    }
}

extern "C" void kernel_launch(void* const* d_in, const int* in_sizes, int n_in,
                              void* d_out, int out_size, void* d_ws, size_t ws_size,
                              hipStream_t stream) {
    const float* x    = (const float*)d_in[0];
    const int*   ei   = (const int*)d_in[1];
    const int*   batch= (const int*)d_in[2];
    const float* W1   = (const float*)d_in[3];
    const float* b1   = (const float*)d_in[4];
    const float* W2   = (const float*)d_in[5];
    const float* b2   = (const float*)d_in[6];
    const float* Wl1  = (const float*)d_in[7];
    const float* bl1  = (const float*)d_in[8];
    const float* Wl2  = (const float*)d_in[9];
    const float* bl2  = (const float*)d_in[10];

    const int N = in_sizes[0];
    const int E = in_sizes[1] / 2;
    const int G = out_size / 4;
    const int* src = ei;
    const int* dst = ei + E;
    const int NBUCK = (N + 63) >> 6;            // 1563
    const int NCH   = (E + CHUNK - 1) / CHUNK;  // 196

    // Workspace (re-poisoned each call; every buffer fully written by kernels,
    // so no memset needed).
    char* p = (char*)d_ws;
    size_t off = 0;
    int*   hist = (int*)(p + off);   off += align_up((size_t)NCH * NBUCK * 4, 16);
    int*   btot = (int*)(p + off);   off += align_up((size_t)NBUCK * 4, 16);
    int*   babs = (int*)(p + off);   off += align_up((size_t)(NBUCK + 1) * 4, 16);
    float* dinv = (float*)(p + off); off += align_up((size_t)N * 4, 16);
    float* xd   = (float*)(p + off); off += align_up((size_t)N * 4, 16);
    int2*  ebuf = (int2*)(p + off);  off += align_up((size_t)E * 8, 16);
    float* h1s  = (float*)(p + off); off += align_up((size_t)N * 64 * 4, 16);
    float* agg1 = (float*)(p + off); off += align_up((size_t)N * 64 * 4, 16);
    (void)ws_size; (void)n_in;

    k_hist     <<<NCH, 256, 0, stream>>>(dst, hist, E, NBUCK);
    k_cscanA   <<<(NBUCK + 255) / 256, 256, 0, stream>>>(hist, btot, NCH, NBUCK);
    k_cscanB   <<<1, 256, 0, stream>>>(btot, babs, NBUCK, E);
    k_scatter  <<<NCH, 256, 0, stream>>>(src, dst, hist, babs, ebuf, E, NBUCK);
    k_deg_dinv <<<NBUCK, 256, 0, stream>>>(ebuf, babs, x, dinv, xd, N);
    k_tacc_h1  <<<NBUCK, 256, 0, stream>>>(ebuf, babs, xd, dinv, W1, b1, h1s, N);
    k_agg1     <<<NBUCK, 256, 0, stream>>>(ebuf, babs, dinv, h1s, agg1, N);
    k_gemm_pool<<<G, 256, 0, stream>>>(agg1, batch, W2, b2, Wl1, bl1, Wl2, bl2,
                                       (float*)d_out, N);
}